// Round 1
// baseline (2393.331 us; speedup 1.0000x reference)
//
#include <hip/hip_runtime.h>
#include <cmath>

// Problem constants (fixed by the reference)
constexpr int TOT = 131072;   // 32 graphs * 4096 nodes
constexpr int NE  = 1048576;  // edges
constexpr int NMASK = 4095;   // N-1, N=4096 (power of 2)

// ---------------- degree / dinv ----------------
__global__ __launch_bounds__(256) void k_deg(const int* __restrict__ dst,
                                             float* __restrict__ deg, int E) {
    int e = blockIdx.x * 256 + threadIdx.x;
    if (e < E) unsafeAtomicAdd(&deg[dst[e]], 1.0f);
}

__global__ __launch_bounds__(256) void k_dinv(float* __restrict__ deg) {
    int i = blockIdx.x * 256 + threadIdx.x;
    deg[i] = 1.0f / sqrtf(deg[i] + 1.0f);   // +1 self-loop
}

// ---------------- xs = x * dinv, dup-write (agg init = self-loop term) ----------------
__global__ __launch_bounds__(256) void k_scale_dup64(const float4* __restrict__ x,
                                                     const float* __restrict__ dinv,
                                                     float4* __restrict__ a,
                                                     float4* __restrict__ b) {
    int t = blockIdx.x * 256 + threadIdx.x;      // t < TOT*16
    int row = t >> 4;
    float d = dinv[row];
    float4 v = x[t];
    v.x *= d; v.y *= d; v.z *= d; v.w *= d;
    a[t] = v; b[t] = v;
}

// ---------------- edge scatter: agg[dst] += xs[src] (C = 4<<LC4 channels) ----------------
template<int LC4>
__global__ __launch_bounds__(256) void k_scatter(const float4* __restrict__ xs,
                                                 float* __restrict__ agg,
                                                 const int* __restrict__ src,
                                                 const int* __restrict__ dst, int E) {
    int t = blockIdx.x * 256 + threadIdx.x;
    int e = t >> LC4;
    if (e >= E) return;
    int g = t & ((1 << LC4) - 1);
    int s = src[e], d = dst[e];
    float4 v = xs[(s << LC4) + g];
    float* p = agg + ((long)(d << LC4) + g) * 4;
    unsafeAtomicAdd(p + 0, v.x);
    unsafeAtomicAdd(p + 1, v.y);
    unsafeAtomicAdd(p + 2, v.z);
    unsafeAtomicAdd(p + 3, v.w);
}

// ---------------- layer-2 epilogue: zs3 = relu(agg2*dinv + b2) * dinv, dup-write ----------------
__global__ __launch_bounds__(256) void k_post2(const float4* __restrict__ agg2,
                                               const float* __restrict__ dinv,
                                               const float4* __restrict__ b2,
                                               float4* __restrict__ a,
                                               float4* __restrict__ b) {
    int t = blockIdx.x * 256 + threadIdx.x;      // t < TOT*8 (32 ch)
    int row = t >> 3;
    int g = t & 7;
    float d = dinv[row];
    float4 v = agg2[t];
    float4 bb = b2[g];
    float4 o;
    o.x = fmaxf(fmaf(v.x, d, bb.x), 0.0f) * d;
    o.y = fmaxf(fmaf(v.y, d, bb.y), 0.0f) * d;
    o.z = fmaxf(fmaf(v.z, d, bb.z), 0.0f) * d;
    o.w = fmaxf(fmaf(v.w, d, bb.w), 0.0f) * d;
    a[t] = o; b[t] = o;
}

// ---------------- conv weight transpose: w[o][c][k] -> wt[k][c][o] ----------------
__global__ __launch_bounds__(256) void k_tr_conv(const float* __restrict__ w,
                                                 float* __restrict__ wt,
                                                 int COUT, int CIN) {
    int i = blockIdx.x * 256 + threadIdx.x;
    int tot = COUT * CIN * 3;
    if (i >= tot) return;
    int o = i / (CIN * 3);
    int rem = i - o * CIN * 3;
    int c = rem / 3;
    int k = rem - c * 3;
    wt[(k * CIN + c) * COUT + o] = w[i];
}

// ---------------- fused dense / conv1d kernel ----------------
// Computes y[row][o] = act( sum_{k,c} wt[(k*CIN+c)*COUT+o] * xin[row+k-HALO][c] + bias[o] )
// with optional input row-scale by dinv (SIN), output row-scale (SOUT), relu, dup-write.
// TAPS=1 -> plain GEMM; TAPS=3 -> temporal conv with zero pad at batch boundaries.
// wt layout for TAPS=1 is just w[c][o] (row-major fan_in x fan_out, as given).
template<int CIN, int COUT, int TAPS, bool SIN, bool SOUT, bool RELU, bool BIAS, bool DUP>
__global__ __launch_bounds__(256) void k_conv(const float* __restrict__ x,
                                              const float* __restrict__ wt,
                                              const float* __restrict__ bias,
                                              const float* __restrict__ dinv,
                                              float* __restrict__ y,
                                              float* __restrict__ y2) {
    constexpr int ROWS = 64;
    constexpr int HALO = (TAPS == 3) ? 1 : 0;
    constexpr int TR = ROWS + 2 * HALO;
    constexpr int SC = CIN + 1;                 // +1 pad: (r+c)%32 banks -> 2-way = free
    constexpr int OPW = COUT / 4;               // outputs per wave (4 waves/block)
    constexpr int LCIN = (CIN == 128) ? 7 : (CIN == 64) ? 6 : 5;
    __shared__ float tile[TR * SC];

    const int R0 = blockIdx.x * ROWS;
    const int n0 = R0 & NMASK;

    for (int idx = threadIdx.x; idx < TR * CIN; idx += 256) {
        int tr = idx >> LCIN;
        int c = idx & (CIN - 1);
        int ro = tr - HALO;
        int grow = R0 + ro;
        bool valid = true;
        if (TAPS == 3) {
            if (ro < 0) valid = (n0 > 0);
            else if (ro >= ROWS) valid = (n0 + ROWS < 4096);
        }
        float v = 0.0f;
        if (valid) {
            v = x[(long)grow * CIN + c];
            if (SIN) v *= dinv[grow];
        }
        tile[tr * SC + c] = v;
    }
    __syncthreads();

    const int r = threadIdx.x & 63;
    const int ob = __builtin_amdgcn_readfirstlane((int)(threadIdx.x >> 6) * OPW);
    const float* __restrict__ w0 = wt + ob;

    float acc[OPW];
#pragma unroll
    for (int j = 0; j < OPW; ++j) acc[j] = 0.0f;

#pragma unroll 4
    for (int c = 0; c < CIN; ++c) {
        if (TAPS == 3) {
            float xm = tile[(r + 0) * SC + c];
            float xc = tile[(r + 1) * SC + c];
            float xp = tile[(r + 2) * SC + c];
#pragma unroll
            for (int j = 0; j < OPW; ++j) {
                acc[j] = fmaf(xm, w0[(0 * CIN + c) * COUT + j], acc[j]);
                acc[j] = fmaf(xc, w0[(1 * CIN + c) * COUT + j], acc[j]);
                acc[j] = fmaf(xp, w0[(2 * CIN + c) * COUT + j], acc[j]);
            }
        } else {
            float xc = tile[r * SC + c];
#pragma unroll
            for (int j = 0; j < OPW; ++j)
                acc[j] = fmaf(xc, w0[c * COUT + j], acc[j]);
        }
    }

    const int row = R0 + r;
    float dv = SOUT ? dinv[row] : 1.0f;
    float4* yv = (float4*)(y + (long)row * COUT + ob);
    float4* yv2 = DUP ? (float4*)(y2 + (long)row * COUT + ob) : nullptr;
#pragma unroll
    for (int j4 = 0; j4 < OPW / 4; ++j4) {
        float o[4];
#pragma unroll
        for (int u = 0; u < 4; ++u) {
            float v = acc[j4 * 4 + u];
            if (BIAS) v += bias[ob + j4 * 4 + u];
            if (RELU) v = fmaxf(v, 0.0f);
            if (SOUT) v *= dv;
            o[u] = v;
        }
        float4 ov = make_float4(o[0], o[1], o[2], o[3]);
        yv[j4] = ov;
        if (DUP) yv2[j4] = ov;
    }
}

// ---------------- heads: pi = sigmoid, nb = softplus, p = sigmoid ----------------
__global__ __launch_bounds__(256) void k_heads(const float* __restrict__ xt,
                                               const float* __restrict__ Wpi, const float* __restrict__ bpi,
                                               const float* __restrict__ Wn,  const float* __restrict__ bn,
                                               const float* __restrict__ Wp,  const float* __restrict__ bp,
                                               float* __restrict__ out) {
    int row = blockIdx.x * 256 + threadIdx.x;
    if (row >= TOT) return;
    const float4* xv = (const float4*)(xt + (long)row * 128);
    float ap = 0.0f, an = 0.0f, aq = 0.0f;
#pragma unroll
    for (int c4 = 0; c4 < 32; ++c4) {
        float4 v = xv[c4];
        int c = c4 * 4;
        ap += v.x * Wpi[c] + v.y * Wpi[c + 1] + v.z * Wpi[c + 2] + v.w * Wpi[c + 3];
        an += v.x * Wn[c]  + v.y * Wn[c + 1]  + v.z * Wn[c + 2]  + v.w * Wn[c + 3];
        aq += v.x * Wp[c]  + v.y * Wp[c + 1]  + v.z * Wp[c + 2]  + v.w * Wp[c + 3];
    }
    float zpi = ap + bpi[0];
    float zn  = an + bn[0];
    float zp  = aq + bp[0];
    out[row] = 1.0f / (1.0f + expf(-zpi));
    out[TOT + row] = (zn > 20.0f) ? zn : log1pf(expf(zn));
    out[2 * TOT + row] = 1.0f / (1.0f + expf(-zp));
}

extern "C" void kernel_launch(void* const* d_in, const int* in_sizes, int n_in,
                              void* d_out, int out_size, void* d_ws, size_t ws_size,
                              hipStream_t stream) {
    const float* x   = (const float*)d_in[0];
    const int*   ei  = (const int*)d_in[1];
    const int*   src = ei;
    const int*   dst = ei + NE;
    // d_in[2] = batch (unused: batch = row >> 12 by construction)
    const float* W1 = (const float*)d_in[3];
    const float* b1 = (const float*)d_in[4];
    const float* W2 = (const float*)d_in[5];
    const float* b2 = (const float*)d_in[6];
    const float* W3 = (const float*)d_in[7];
    const float* b3 = (const float*)d_in[8];
    const float* tW1 = (const float*)d_in[9];
    const float* tb1 = (const float*)d_in[10];
    const float* tW2 = (const float*)d_in[11];
    const float* tb2 = (const float*)d_in[12];
    const float* tW3 = (const float*)d_in[13];
    const float* tb3 = (const float*)d_in[14];
    const float* Wpi = (const float*)d_in[15];
    const float* bpi = (const float*)d_in[16];
    const float* Wn  = (const float*)d_in[17];
    const float* bn  = (const float*)d_in[18];
    const float* Wp  = (const float*)d_in[19];
    const float* bp  = (const float*)d_in[20];

    // Workspace layout (~210 MB total)
    char* ws = (char*)d_ws;
    float* dinv = (float*)(ws);                               // 512 KB
    float* tw1t = (float*)(ws + (1ull << 20));                // 192 KB
    float* tw2t = (float*)(ws + (1ull << 20) + (256 << 10));  // 48 KB
    float* tw3t = (float*)(ws + (1ull << 20) + (320 << 10));  // 48 KB
    float* bufA = (float*)(ws + (2ull << 20));                // 64 MB
    float* bufB = (float*)(ws + (66ull << 20));               // 64 MB
    float* bufC = (float*)(ws + (130ull << 20));              // 64 MB
    float* bufD = (float*)(ws + (194ull << 20));              // 16 MB

    // prep: deg=0, transpose conv weights to [k][c][o]
    hipMemsetAsync(dinv, 0, TOT * sizeof(float), stream);
    k_tr_conv<<<192, 256, 0, stream>>>(tW1, tw1t, 128, 128);
    k_tr_conv<<<48, 256, 0, stream>>>(tW2, tw2t, 32, 128);
    k_tr_conv<<<48, 256, 0, stream>>>(tW3, tw3t, 128, 32);

    // degree + dinv
    k_deg<<<NE / 256, 256, 0, stream>>>(dst, dinv, NE);
    k_dinv<<<TOT / 256, 256, 0, stream>>>(dinv);

    // ---- GCN layer 1 (aggregate in 64ch, then GEMM 64->128) ----
    k_scale_dup64<<<TOT * 16 / 256, 256, 0, stream>>>((const float4*)x, dinv,
                                                      (float4*)bufA, (float4*)bufB);
    k_scatter<4><<<NE * 16 / 256, 256, 0, stream>>>((const float4*)bufA, bufB, src, dst, NE);
    // h1 = relu((agg1*dinv) @ W1 + b1)  -> bufC [TOT,128]
    k_conv<64, 128, 1, true, false, true, true, false>
        <<<TOT / 64, 256, 0, stream>>>(bufB, W1, b1, dinv, bufC, nullptr);

    // ---- GCN layer 2 (GEMM 128->32, then aggregate in 32ch) ----
    // zs2 = (h1 @ W2) * dinv -> bufA, agg2 init -> bufD
    k_conv<128, 32, 1, false, true, false, false, true>
        <<<TOT / 64, 256, 0, stream>>>(bufC, W2, nullptr, dinv, bufA, bufD);
    k_scatter<3><<<NE * 8 / 256, 256, 0, stream>>>((const float4*)bufA, bufD, src, dst, NE);
    // zs3 = relu(agg2*dinv + b2)*dinv -> bufA, agg3 init -> bufB
    k_post2<<<TOT * 8 / 256, 256, 0, stream>>>((const float4*)bufD, dinv,
                                               (const float4*)b2, (float4*)bufA, (float4*)bufB);

    // ---- GCN layer 3 (aggregate in 32ch, then GEMM 32->128) ----
    k_scatter<3><<<NE * 8 / 256, 256, 0, stream>>>((const float4*)bufA, bufB, src, dst, NE);
    // h3 = relu((agg3*dinv) @ W3 + b3) -> bufC [TOT,128]
    k_conv<32, 128, 1, true, false, true, true, false>
        <<<TOT / 64, 256, 0, stream>>>(bufB, W3, b3, dinv, bufC, nullptr);

    // ---- temporal convs (k=3, pad 1, along rows within each batch of 4096) ----
    k_conv<128, 128, 3, false, false, true, true, false>
        <<<TOT / 64, 256, 0, stream>>>(bufC, tw1t, tb1, nullptr, bufA, nullptr);
    k_conv<128, 32, 3, false, false, true, true, false>
        <<<TOT / 64, 256, 0, stream>>>(bufA, tw2t, tb2, nullptr, bufD, nullptr);
    k_conv<32, 128, 3, false, false, true, true, false>
        <<<TOT / 64, 256, 0, stream>>>(bufD, tw3t, tb3, nullptr, bufB, nullptr);

    // ---- heads ----
    k_heads<<<TOT / 256, 256, 0, stream>>>(bufB, Wpi, bpi, Wn, bn, Wp, bp, (float*)d_out);
}

// Round 2
// 778.336 us; speedup vs baseline: 3.0749x; 3.0749x over previous
//
#include <hip/hip_runtime.h>
#include <cmath>

// Problem constants (fixed by the reference)
constexpr int TOT = 131072;   // 32 graphs * 4096 nodes
constexpr int NE  = 1048576;  // edges
constexpr int NMASK = 4095;   // N-1, N=4096 (power of 2)

// ================= CSR build =================

__global__ __launch_bounds__(256) void k_count(const int* __restrict__ dst,
                                               int* __restrict__ cnt, int E) {
    int e = blockIdx.x * 256 + threadIdx.x;
    if (e < E) atomicAdd(&cnt[dst[e]], 1);
}

__global__ __launch_bounds__(256) void k_dinv(const int* __restrict__ cnt,
                                              float* __restrict__ dinv) {
    int i = blockIdx.x * 256 + threadIdx.x;
    dinv[i] = rsqrtf((float)cnt[i] + 1.0f);   // +1 self-loop
}

// per-block (512-elem) sums
__global__ __launch_bounds__(256) void k_bsum(const int* __restrict__ cnt,
                                              int* __restrict__ bsum) {
    __shared__ int sm[256];
    int bid = blockIdx.x, tid = threadIdx.x;
    int base = bid * 512;
    sm[tid] = cnt[base + tid] + cnt[base + 256 + tid];
    __syncthreads();
    for (int off = 128; off > 0; off >>= 1) {
        if (tid < off) sm[tid] += sm[tid + off];
        __syncthreads();
    }
    if (tid == 0) bsum[bid] = sm[0];
}

// exclusive scan of 256 block sums (single block)
__global__ __launch_bounds__(256) void k_bscan(const int* __restrict__ bsum,
                                               int* __restrict__ boff) {
    __shared__ int sm[256];
    int tid = threadIdx.x;
    int v = bsum[tid];
    sm[tid] = v;
    __syncthreads();
    for (int off = 1; off < 256; off <<= 1) {
        int a = sm[tid];
        int b = (tid >= off) ? sm[tid - off] : 0;
        __syncthreads();
        sm[tid] = a + b;
        __syncthreads();
    }
    boff[tid] = sm[tid] - v;
}

// local exclusive scan (512 elems/block) + block offset -> row_start
__global__ __launch_bounds__(256) void k_scan(const int* __restrict__ cnt,
                                              const int* __restrict__ boff,
                                              int* __restrict__ rs) {
    __shared__ int sm[256];
    int bid = blockIdx.x, tid = threadIdx.x;
    int base = bid * 512 + tid * 2;
    int a0 = cnt[base], a1 = cnt[base + 1];
    int t = a0 + a1;
    sm[tid] = t;
    __syncthreads();
    for (int off = 1; off < 256; off <<= 1) {
        int a = sm[tid];
        int b = (tid >= off) ? sm[tid - off] : 0;
        __syncthreads();
        sm[tid] = a + b;
        __syncthreads();
    }
    int excl = sm[tid] - t + boff[bid];
    rs[base] = excl;
    rs[base + 1] = excl + a0;
    if (bid == 0 && tid == 0) rs[TOT] = NE;
}

__global__ __launch_bounds__(256) void k_fill(const int* __restrict__ src,
                                              const int* __restrict__ dst,
                                              const int* __restrict__ rs,
                                              int* __restrict__ cur,
                                              int* __restrict__ csr, int E) {
    int e = blockIdx.x * 256 + threadIdx.x;
    if (e >= E) return;
    int d = dst[e];
    int p = atomicAdd(&cur[d], 1);
    csr[rs[d] + p] = src[e];
}

// ================= node-wise kernels =================

// xs = x * dinv (64 ch)
__global__ __launch_bounds__(256) void k_scale64(const float4* __restrict__ x,
                                                 const float* __restrict__ dinv,
                                                 float4* __restrict__ a) {
    int t = blockIdx.x * 256 + threadIdx.x;      // t < TOT*16
    int row = t >> 4;
    float d = dinv[row];
    float4 v = x[t];
    v.x *= d; v.y *= d; v.z *= d; v.w *= d;
    a[t] = v;
}

// CSR gather: out[d] = xs[d] + sum_{e in in(d)} xs[csr[e]]   (C = 4<<LC4 channels)
// EPI==1: out = relu(acc*dinv + bias)*dinv   (layer-2 epilogue, pre-scaled for layer 3)
template<int LC4, int EPI>
__global__ __launch_bounds__(256) void k_gather(const float4* __restrict__ xs,
                                                const int* __restrict__ rs,
                                                const int* __restrict__ csr,
                                                const float* __restrict__ dinv,
                                                const float4* __restrict__ bias,
                                                float4* __restrict__ out) {
    int t = blockIdx.x * 256 + threadIdx.x;      // t < TOT << LC4
    int d = t >> LC4;
    int g = t & ((1 << LC4) - 1);
    float4 acc = xs[t];                          // self-loop term
    int e0 = rs[d], e1 = rs[d + 1];
    for (int e = e0; e < e1; ++e) {
        int s = csr[e];
        float4 v = xs[(s << LC4) + g];
        acc.x += v.x; acc.y += v.y; acc.z += v.z; acc.w += v.w;
    }
    if (EPI == 1) {
        float dv = dinv[d];
        float4 bb = bias[g];
        acc.x = fmaxf(fmaf(acc.x, dv, bb.x), 0.0f) * dv;
        acc.y = fmaxf(fmaf(acc.y, dv, bb.y), 0.0f) * dv;
        acc.z = fmaxf(fmaf(acc.z, dv, bb.z), 0.0f) * dv;
        acc.w = fmaxf(fmaf(acc.w, dv, bb.w), 0.0f) * dv;
    }
    out[t] = acc;
}

// ---------------- conv weight transpose: w[o][c][k] -> wt[k][c][o] ----------------
__global__ __launch_bounds__(256) void k_tr_conv(const float* __restrict__ w,
                                                 float* __restrict__ wt,
                                                 int COUT, int CIN) {
    int i = blockIdx.x * 256 + threadIdx.x;
    int tot = COUT * CIN * 3;
    if (i >= tot) return;
    int o = i / (CIN * 3);
    int rem = i - o * CIN * 3;
    int c = rem / 3;
    int k = rem - c * 3;
    wt[(k * CIN + c) * COUT + o] = w[i];
}

// ---------------- fused dense / conv1d kernel ----------------
// y[row][o] = act( sum_{k,c} wt[(k*CIN+c)*COUT+o] * xin[row+k-HALO][c] + bias[o] )
// SIN: input row-scale by dinv; SOUT: output row-scale; TAPS=1 -> GEMM (wt = w[c][o]).
template<int CIN, int COUT, int TAPS, bool SIN, bool SOUT, bool RELU, bool BIAS>
__global__ __launch_bounds__(256) void k_conv(const float* __restrict__ x,
                                              const float* __restrict__ wt,
                                              const float* __restrict__ bias,
                                              const float* __restrict__ dinv,
                                              float* __restrict__ y) {
    constexpr int ROWS = 64;
    constexpr int HALO = (TAPS == 3) ? 1 : 0;
    constexpr int TR = ROWS + 2 * HALO;
    constexpr int SC = CIN + 1;                 // +1 pad: 2-way bank aliasing = free
    constexpr int OPW = COUT / 4;               // outputs per wave (4 waves/block)
    constexpr int LCIN = (CIN == 128) ? 7 : (CIN == 64) ? 6 : 5;
    __shared__ float tile[TR * SC];

    const int R0 = blockIdx.x * ROWS;
    const int n0 = R0 & NMASK;

    for (int idx = threadIdx.x; idx < TR * CIN; idx += 256) {
        int tr = idx >> LCIN;
        int c = idx & (CIN - 1);
        int ro = tr - HALO;
        int grow = R0 + ro;
        bool valid = true;
        if (TAPS == 3) {
            if (ro < 0) valid = (n0 > 0);
            else if (ro >= ROWS) valid = (n0 + ROWS < 4096);
        }
        float v = 0.0f;
        if (valid) {
            v = x[(long)grow * CIN + c];
            if (SIN) v *= dinv[grow];
        }
        tile[tr * SC + c] = v;
    }
    __syncthreads();

    const int r = threadIdx.x & 63;
    const int ob = __builtin_amdgcn_readfirstlane((int)(threadIdx.x >> 6) * OPW);
    const float* __restrict__ w0 = wt + ob;

    float acc[OPW];
#pragma unroll
    for (int j = 0; j < OPW; ++j) acc[j] = 0.0f;

#pragma unroll 4
    for (int c = 0; c < CIN; ++c) {
        if (TAPS == 3) {
            float xm = tile[(r + 0) * SC + c];
            float xc = tile[(r + 1) * SC + c];
            float xp = tile[(r + 2) * SC + c];
#pragma unroll
            for (int j = 0; j < OPW; ++j) {
                acc[j] = fmaf(xm, w0[(0 * CIN + c) * COUT + j], acc[j]);
                acc[j] = fmaf(xc, w0[(1 * CIN + c) * COUT + j], acc[j]);
                acc[j] = fmaf(xp, w0[(2 * CIN + c) * COUT + j], acc[j]);
            }
        } else {
            float xc = tile[r * SC + c];
#pragma unroll
            for (int j = 0; j < OPW; ++j)
                acc[j] = fmaf(xc, w0[c * COUT + j], acc[j]);
        }
    }

    const int row = R0 + r;
    float dv = SOUT ? dinv[row] : 1.0f;
    float4* yv = (float4*)(y + (long)row * COUT + ob);
#pragma unroll
    for (int j4 = 0; j4 < OPW / 4; ++j4) {
        float o[4];
#pragma unroll
        for (int u = 0; u < 4; ++u) {
            float v = acc[j4 * 4 + u];
            if (BIAS) v += bias[ob + j4 * 4 + u];
            if (RELU) v = fmaxf(v, 0.0f);
            if (SOUT) v *= dv;
            o[u] = v;
        }
        yv[j4] = make_float4(o[0], o[1], o[2], o[3]);
    }
}

// ---------------- heads: pi = sigmoid, nb = softplus, p = sigmoid ----------------
__global__ __launch_bounds__(256) void k_heads(const float* __restrict__ xt,
                                               const float* __restrict__ Wpi, const float* __restrict__ bpi,
                                               const float* __restrict__ Wn,  const float* __restrict__ bn,
                                               const float* __restrict__ Wp,  const float* __restrict__ bp,
                                               float* __restrict__ out) {
    int row = blockIdx.x * 256 + threadIdx.x;
    if (row >= TOT) return;
    const float4* xv = (const float4*)(xt + (long)row * 128);
    float ap = 0.0f, an = 0.0f, aq = 0.0f;
#pragma unroll
    for (int c4 = 0; c4 < 32; ++c4) {
        float4 v = xv[c4];
        int c = c4 * 4;
        ap += v.x * Wpi[c] + v.y * Wpi[c + 1] + v.z * Wpi[c + 2] + v.w * Wpi[c + 3];
        an += v.x * Wn[c]  + v.y * Wn[c + 1]  + v.z * Wn[c + 2]  + v.w * Wn[c + 3];
        aq += v.x * Wp[c]  + v.y * Wp[c + 1]  + v.z * Wp[c + 2]  + v.w * Wp[c + 3];
    }
    float zpi = ap + bpi[0];
    float zn  = an + bn[0];
    float zp  = aq + bp[0];
    out[row] = 1.0f / (1.0f + expf(-zpi));
    out[TOT + row] = (zn > 20.0f) ? zn : log1pf(expf(zn));
    out[2 * TOT + row] = 1.0f / (1.0f + expf(-zp));
}

extern "C" void kernel_launch(void* const* d_in, const int* in_sizes, int n_in,
                              void* d_out, int out_size, void* d_ws, size_t ws_size,
                              hipStream_t stream) {
    const float* x   = (const float*)d_in[0];
    const int*   ei  = (const int*)d_in[1];
    const int*   src = ei;
    const int*   dst = ei + NE;
    // d_in[2] = batch (unused: batch = row >> 12 by construction)
    const float* W1 = (const float*)d_in[3];
    const float* b1 = (const float*)d_in[4];
    const float* W2 = (const float*)d_in[5];
    const float* b2 = (const float*)d_in[6];
    const float* W3 = (const float*)d_in[7];
    const float* b3 = (const float*)d_in[8];
    const float* tW1 = (const float*)d_in[9];
    const float* tb1 = (const float*)d_in[10];
    const float* tW2 = (const float*)d_in[11];
    const float* tb2 = (const float*)d_in[12];
    const float* tW3 = (const float*)d_in[13];
    const float* tb3 = (const float*)d_in[14];
    const float* Wpi = (const float*)d_in[15];
    const float* bpi = (const float*)d_in[16];
    const float* Wn  = (const float*)d_in[17];
    const float* bn  = (const float*)d_in[18];
    const float* Wp  = (const float*)d_in[19];
    const float* bp  = (const float*)d_in[20];

    // ---- workspace layout (~190 MB) ----
    char* ws = (char*)d_ws;
    float* dinv = (float*)(ws + (0ull  << 20));   // 512 KB
    int*   cnt  = (int*)  (ws + (1ull  << 20));   // 512 KB
    int*   cur  = (int*)  (ws + (2ull  << 20));   // 512 KB
    int*   rs   = (int*)  (ws + (3ull  << 20));   // 512 KB + 4 B
    int*   bsum = (int*)  (ws + (4ull  << 20));   // 1 KB
    int*   boff = (int*)  (ws + (4ull  << 20) + (64 << 10));
    float* tw1t = (float*)(ws + (5ull  << 20));   // 192 KB
    float* tw2t = (float*)(ws + (5ull  << 20) + (256 << 10));  // 48 KB
    float* tw3t = (float*)(ws + (5ull  << 20) + (512 << 10));  // 48 KB
    int*   csr  = (int*)  (ws + (6ull  << 20));   // 4 MB
    float* B1   = (float*)(ws + (16ull << 20));   // 68 MB (128ch slot)
    float* B2   = (float*)(ws + (86ull << 20));   // 68 MB (128ch slot)
    float* B3   = (float*)(ws + (156ull<< 20));   // 34 MB (64ch slot)

    // ---- prep: zero counts/cursors, transpose conv weights ----
    hipMemsetAsync(cnt, 0, TOT * sizeof(int), stream);
    hipMemsetAsync(cur, 0, TOT * sizeof(int), stream);
    k_tr_conv<<<192, 256, 0, stream>>>(tW1, tw1t, 128, 128);
    k_tr_conv<<<48, 256, 0, stream>>>(tW2, tw2t, 32, 128);
    k_tr_conv<<<48, 256, 0, stream>>>(tW3, tw3t, 128, 32);

    // ---- CSR build + dinv ----
    k_count<<<NE / 256, 256, 0, stream>>>(dst, cnt, NE);
    k_dinv<<<TOT / 256, 256, 0, stream>>>(cnt, dinv);
    k_bsum<<<256, 256, 0, stream>>>(cnt, bsum);
    k_bscan<<<1, 256, 0, stream>>>(bsum, boff);
    k_scan<<<256, 256, 0, stream>>>(cnt, boff, rs);
    k_fill<<<NE / 256, 256, 0, stream>>>(src, dst, rs, cur, csr, NE);

    // ---- GCN layer 1 (aggregate in 64ch, then GEMM 64->128) ----
    k_scale64<<<TOT * 16 / 256, 256, 0, stream>>>((const float4*)x, dinv, (float4*)B3);
    k_gather<4, 0><<<TOT * 16 / 256, 256, 0, stream>>>((const float4*)B3, rs, csr, dinv,
                                                       nullptr, (float4*)B1);
    // h1 = relu((agg1*dinv) @ W1 + b1) -> B2 [TOT,128]
    k_conv<64, 128, 1, true, false, true, true>
        <<<TOT / 64, 256, 0, stream>>>(B1, W1, b1, dinv, B2);

    // ---- GCN layer 2 (GEMM 128->32, then aggregate in 32ch) ----
    // zs2 = (h1 @ W2) * dinv -> B1
    k_conv<128, 32, 1, false, true, false, false>
        <<<TOT / 64, 256, 0, stream>>>(B2, W2, nullptr, dinv, B1);
    // zs3 = relu(gather(zs2)*dinv + b2)*dinv -> B3
    k_gather<3, 1><<<TOT * 8 / 256, 256, 0, stream>>>((const float4*)B1, rs, csr, dinv,
                                                      (const float4*)b2, (float4*)B3);

    // ---- GCN layer 3 (aggregate in 32ch, then GEMM 32->128) ----
    k_gather<3, 0><<<TOT * 8 / 256, 256, 0, stream>>>((const float4*)B3, rs, csr, dinv,
                                                      nullptr, (float4*)B1);
    // h3 = relu((agg3*dinv) @ W3 + b3) -> B2 [TOT,128]
    k_conv<32, 128, 1, true, false, true, true>
        <<<TOT / 64, 256, 0, stream>>>(B1, W3, b3, dinv, B2);

    // ---- temporal convs (k=3, pad 1, rows contiguous within each batch of 4096) ----
    k_conv<128, 128, 3, false, false, true, true>
        <<<TOT / 64, 256, 0, stream>>>(B2, tw1t, tb1, nullptr, B1);
    k_conv<128, 32, 3, false, false, true, true>
        <<<TOT / 64, 256, 0, stream>>>(B1, tw2t, tb2, nullptr, B3);
    k_conv<32, 128, 3, false, false, true, true>
        <<<TOT / 64, 256, 0, stream>>>(B3, tw3t, tb3, nullptr, B2);

    // ---- heads ----
    k_heads<<<TOT / 256, 256, 0, stream>>>(B2, Wpi, bpi, Wn, bn, Wp, bp, (float*)d_out);
}

// Round 3
// 412.321 us; speedup vs baseline: 5.8045x; 1.8877x over previous
//
#include <hip/hip_runtime.h>
#include <cmath>

// Problem constants (fixed by the reference)
constexpr int TOT = 131072;   // 32 graphs * 4096 nodes
constexpr int NE  = 1048576;  // edges
constexpr int NMASK = 4095;   // N-1, N=4096

typedef __attribute__((ext_vector_type(8))) short bf16x8;
typedef __attribute__((ext_vector_type(4))) float f32x4;

// ---- bf16 helpers (RNE) ----
__device__ inline float bf2f(unsigned int u16) {
    union { unsigned int i; float f; } x; x.i = u16 << 16; return x.f;
}
__device__ inline unsigned short f2bf(float f) {
    union { float f; unsigned int i; } x; x.f = f;
    unsigned int r = (x.i + 0x7fffu + ((x.i >> 16) & 1u)) >> 16;
    return (unsigned short)r;
}
__device__ inline void unpack8(uint4 v, float* f) {
    f[0] = bf2f(v.x & 0xffffu); f[1] = bf2f(v.x >> 16);
    f[2] = bf2f(v.y & 0xffffu); f[3] = bf2f(v.y >> 16);
    f[4] = bf2f(v.z & 0xffffu); f[5] = bf2f(v.z >> 16);
    f[6] = bf2f(v.w & 0xffffu); f[7] = bf2f(v.w >> 16);
}
__device__ inline uint4 pack8(const float* f) {
    uint4 v;
    v.x = (unsigned)f2bf(f[0]) | ((unsigned)f2bf(f[1]) << 16);
    v.y = (unsigned)f2bf(f[2]) | ((unsigned)f2bf(f[3]) << 16);
    v.z = (unsigned)f2bf(f[4]) | ((unsigned)f2bf(f[5]) << 16);
    v.w = (unsigned)f2bf(f[6]) | ((unsigned)f2bf(f[7]) << 16);
    return v;
}

// ================= CSR build =================

__global__ __launch_bounds__(256) void k_count(const int* __restrict__ dst,
                                               int* __restrict__ cnt, int E) {
    int e = blockIdx.x * 256 + threadIdx.x;
    if (e < E) atomicAdd(&cnt[dst[e]], 1);
}

__global__ __launch_bounds__(256) void k_dinv(const int* __restrict__ cnt,
                                              float* __restrict__ dinv) {
    int i = blockIdx.x * 256 + threadIdx.x;
    dinv[i] = rsqrtf((float)cnt[i] + 1.0f);   // +1 self-loop
}

__global__ __launch_bounds__(256) void k_bsum(const int* __restrict__ cnt,
                                              int* __restrict__ bsum) {
    __shared__ int sm[256];
    int bid = blockIdx.x, tid = threadIdx.x;
    int base = bid * 512;
    sm[tid] = cnt[base + tid] + cnt[base + 256 + tid];
    __syncthreads();
    for (int off = 128; off > 0; off >>= 1) {
        if (tid < off) sm[tid] += sm[tid + off];
        __syncthreads();
    }
    if (tid == 0) bsum[bid] = sm[0];
}

__global__ __launch_bounds__(256) void k_bscan(const int* __restrict__ bsum,
                                               int* __restrict__ boff) {
    __shared__ int sm[256];
    int tid = threadIdx.x;
    int v = bsum[tid];
    sm[tid] = v;
    __syncthreads();
    for (int off = 1; off < 256; off <<= 1) {
        int a = sm[tid];
        int b = (tid >= off) ? sm[tid - off] : 0;
        __syncthreads();
        sm[tid] = a + b;
        __syncthreads();
    }
    boff[tid] = sm[tid] - v;
}

__global__ __launch_bounds__(256) void k_scan(const int* __restrict__ cnt,
                                              const int* __restrict__ boff,
                                              int* __restrict__ rs) {
    __shared__ int sm[256];
    int bid = blockIdx.x, tid = threadIdx.x;
    int base = bid * 512 + tid * 2;
    int a0 = cnt[base], a1 = cnt[base + 1];
    int t = a0 + a1;
    sm[tid] = t;
    __syncthreads();
    for (int off = 1; off < 256; off <<= 1) {
        int a = sm[tid];
        int b = (tid >= off) ? sm[tid - off] : 0;
        __syncthreads();
        sm[tid] = a + b;
        __syncthreads();
    }
    int excl = sm[tid] - t + boff[bid];
    rs[base] = excl;
    rs[base + 1] = excl + a0;
    if (bid == 0 && tid == 0) rs[TOT] = NE;
}

__global__ __launch_bounds__(256) void k_fill(const int* __restrict__ src,
                                              const int* __restrict__ dst,
                                              const int* __restrict__ rs,
                                              int* __restrict__ cur,
                                              int* __restrict__ csr, int E) {
    int e = blockIdx.x * 256 + threadIdx.x;
    if (e >= E) return;
    int d = dst[e];
    int p = atomicAdd(&cur[d], 1);
    csr[rs[d] + p] = src[e];
}

// ================= weight packing into MFMA B-fragment order =================
// reader: lane reads wp[((kc*NT + nt)*64 + lane)*8 + j] = W[kc*32+(lane>>4)*8+j][nt*16+(lane&15)]
// taps==1: W row-major [K][COUT]; taps==3: original conv w[COUT][CIN][3], k = t*CIN + c.
__global__ __launch_bounds__(256) void k_pack(const float* __restrict__ w,
                                              unsigned short* __restrict__ wp,
                                              int K, int CIN, int COUT, int taps) {
    int idx = blockIdx.x * 256 + threadIdx.x;
    if (idx >= K * COUT) return;
    int j = idx & 7;
    int L = (idx >> 3) & 63;
    int f = idx >> 9;
    int NT = COUT >> 4;
    int kc = f / NT, nt = f - kc * NT;
    int k = kc * 32 + (L >> 4) * 8 + j;
    int n = nt * 16 + (L & 15);
    float v;
    if (taps == 1) v = w[k * COUT + n];
    else { int t = k / CIN, c = k - t * CIN; v = w[(n * CIN + c) * 3 + t]; }
    wp[idx] = f2bf(v);
}

// ================= node-wise =================

// xs = x * dinv -> bf16 (64 ch); one thread = 8 channels
__global__ __launch_bounds__(256) void k_scale64b(const float4* __restrict__ x,
                                                  const float* __restrict__ dinv,
                                                  uint4* __restrict__ out) {
    int t = blockIdx.x * 256 + threadIdx.x;   // t < TOT*8
    int row = t >> 3;
    float d = dinv[row];
    float4 v0 = x[t * 2], v1 = x[t * 2 + 1];
    float f[8] = { v0.x * d, v0.y * d, v0.z * d, v0.w * d,
                   v1.x * d, v1.y * d, v1.z * d, v1.w * d };
    out[t] = pack8(f);
}

// CSR gather over bf16 rows, fp32 accumulate. LC = log2(C/8) (threads per row).
// EPI==2: out = acc * dinv[d]          (pre-scale for the following GEMM)
// EPI==1: out = relu(acc*dinv + bias)*dinv   (layer-2 epilogue)
template<int LC, int EPI>
__global__ __launch_bounds__(256) void k_gatherb(const uint4* __restrict__ xs,
                                                 const int* __restrict__ rs,
                                                 const int* __restrict__ csr,
                                                 const float* __restrict__ dinv,
                                                 const float* __restrict__ bias,
                                                 uint4* __restrict__ out) {
    int t = blockIdx.x * 256 + threadIdx.x;   // t < TOT << LC
    int d = t >> LC;
    int g = t & ((1 << LC) - 1);
    float a[8];
    unpack8(xs[t], a);                        // self-loop term
    int e0 = rs[d], e1 = rs[d + 1];
    for (int e = e0; e < e1; ++e) {
        int s = csr[e];
        float f[8];
        unpack8(xs[(s << LC) + g], f);
#pragma unroll
        for (int j = 0; j < 8; ++j) a[j] += f[j];
    }
    float dv = dinv[d];
    if (EPI == 1) {
#pragma unroll
        for (int j = 0; j < 8; ++j)
            a[j] = fmaxf(fmaf(a[j], dv, bias[g * 8 + j]), 0.0f) * dv;
    } else {
#pragma unroll
        for (int j = 0; j < 8; ++j) a[j] *= dv;
    }
    out[t] = pack8(a);
}

// ================= MFMA dense / conv1d =================
// Y[row][n] = act( sum_{t,c} X[row+t-1][c] * W[t*CIN+c][n] + bias[n] ) (TAPS=3)
// or plain GEMM (TAPS=1). X,Y bf16; W packed by k_pack; fp32 accumulate.
template<int CIN, int COUT, int TAPS, bool RELU, bool BIAS, bool SOUT>
__global__ __launch_bounds__(256) void k_mm(const unsigned short* __restrict__ x,
                                            const bf16x8* __restrict__ wp,
                                            const float* __restrict__ bias,
                                            const float* __restrict__ dinv,
                                            unsigned short* __restrict__ y) {
    constexpr int ROWS = 64;
    constexpr int HALO = (TAPS == 3) ? 1 : 0;
    constexpr int TR = ROWS + 2 * HALO;
    constexpr int SC = CIN + 8;               // stride 17/9/5 bank-quads: conflict-free b128
    constexpr int NCH = CIN / 32;             // K-chunks per tap
    constexpr int NK = TAPS * NCH;            // K-steps
    constexpr int NT = COUT / 16;             // col tiles total
    constexpr int WN = (COUT == 128) ? 2 : 1; // col tiles per wave
    constexpr int WM = (COUT == 128) ? 4 : 2; // row tiles per wave
    __shared__ __attribute__((aligned(16))) unsigned short tile[TR * SC];

    const int R0 = blockIdx.x * ROWS;
    const int n0 = R0 & NMASK; (void)n0;

    // stage X tile (bf16) into LDS, zero-padded halo at batch boundaries
    constexpr int NLD = TR * (CIN / 8);
    for (int idx = threadIdx.x; idx < NLD; idx += 256) {
        int tr = idx / (CIN / 8);
        int c8 = idx - tr * (CIN / 8);
        int ro = tr - HALO;
        bool valid = true;
        if (TAPS == 3) {
            if (ro < 0) valid = (n0 > 0);
            else if (ro >= ROWS) valid = (n0 + ROWS < 4096);
        }
        uint4 v = make_uint4(0, 0, 0, 0);
        if (valid) v = *(const uint4*)(x + (long)(R0 + ro) * CIN + c8 * 8);
        *(uint4*)(tile + tr * SC + c8 * 8) = v;
    }
    __syncthreads();

    const int lane = threadIdx.x & 63;
    const int w = threadIdx.x >> 6;
    const int l16 = lane & 15;
    const int q = lane >> 4;
    const int colbase = (COUT == 128) ? w * 32 : (w & 1) * 16;
    const int rowbase = (COUT == 128) ? 0 : (w >> 1) * 32;
    const int nt0 = colbase >> 4;

    f32x4 acc[WM][WN];
#pragma unroll
    for (int wm = 0; wm < WM; ++wm)
#pragma unroll
        for (int nt = 0; nt < WN; ++nt) acc[wm][nt] = (f32x4){0.f, 0.f, 0.f, 0.f};

    const bf16x8* __restrict__ wpl = wp + lane;

#pragma unroll
    for (int kc = 0; kc < NK; ++kc) {
        const int tap = (TAPS == 3) ? (kc / NCH) : 0;
        const int ch  = (TAPS == 3) ? (kc - tap * NCH) : kc;
        bf16x8 a[WM];
#pragma unroll
        for (int wm = 0; wm < WM; ++wm)
            a[wm] = *(const bf16x8*)(tile + (rowbase + wm * 16 + l16 + tap) * SC + ch * 32 + q * 8);
        bf16x8 b[WN];
#pragma unroll
        for (int nt = 0; nt < WN; ++nt)
            b[nt] = wpl[(kc * NT + nt0 + nt) * 64];
#pragma unroll
        for (int wm = 0; wm < WM; ++wm)
#pragma unroll
            for (int nt = 0; nt < WN; ++nt)
                acc[wm][nt] = __builtin_amdgcn_mfma_f32_16x16x32_bf16(a[wm], b[nt], acc[wm][nt], 0, 0, 0);
    }

    // epilogue: C/D layout col=lane&15, row=q*4+reg
#pragma unroll
    for (int wm = 0; wm < WM; ++wm) {
#pragma unroll
        for (int nt = 0; nt < WN; ++nt) {
            int col = colbase + nt * 16 + l16;
            float bi = BIAS ? bias[col] : 0.0f;
#pragma unroll
            for (int r = 0; r < 4; ++r) {
                int row = R0 + rowbase + wm * 16 + q * 4 + r;
                float v = acc[wm][nt][r] + bi;
                if (RELU) v = fmaxf(v, 0.0f);
                if (SOUT) v *= dinv[row];
                y[(long)row * COUT + col] = f2bf(v);
            }
        }
    }
}

// ================= heads (bf16 in, fp32 out) =================
__global__ __launch_bounds__(256) void k_heads(const unsigned short* __restrict__ xt,
                                               const float* __restrict__ Wpi, const float* __restrict__ bpi,
                                               const float* __restrict__ Wn,  const float* __restrict__ bn,
                                               const float* __restrict__ Wp,  const float* __restrict__ bp,
                                               float* __restrict__ out) {
    int row = blockIdx.x * 256 + threadIdx.x;
    if (row >= TOT) return;
    const uint4* xv = (const uint4*)(xt + (long)row * 128);
    float ap = 0.0f, an = 0.0f, aq = 0.0f;
#pragma unroll
    for (int c8 = 0; c8 < 16; ++c8) {
        float f[8];
        unpack8(xv[c8], f);
        int c = c8 * 8;
#pragma unroll
        for (int j = 0; j < 8; ++j) {
            ap = fmaf(f[j], Wpi[c + j], ap);
            an = fmaf(f[j], Wn[c + j], an);
            aq = fmaf(f[j], Wp[c + j], aq);
        }
    }
    float zpi = ap + bpi[0];
    float zn  = an + bn[0];
    float zp  = aq + bp[0];
    out[row] = 1.0f / (1.0f + expf(-zpi));
    out[TOT + row] = (zn > 20.0f) ? zn : log1pf(expf(zn));
    out[2 * TOT + row] = 1.0f / (1.0f + expf(-zp));
}

extern "C" void kernel_launch(void* const* d_in, const int* in_sizes, int n_in,
                              void* d_out, int out_size, void* d_ws, size_t ws_size,
                              hipStream_t stream) {
    const float* x   = (const float*)d_in[0];
    const int*   ei  = (const int*)d_in[1];
    const int*   src = ei;
    const int*   dst = ei + NE;
    const float* W1 = (const float*)d_in[3];
    const float* b1 = (const float*)d_in[4];
    const float* W2 = (const float*)d_in[5];
    const float* b2 = (const float*)d_in[6];
    const float* W3 = (const float*)d_in[7];
    const float* b3 = (const float*)d_in[8];
    const float* tW1 = (const float*)d_in[9];
    const float* tb1 = (const float*)d_in[10];
    const float* tW2 = (const float*)d_in[11];
    const float* tb2 = (const float*)d_in[12];
    const float* tW3 = (const float*)d_in[13];
    const float* tb3 = (const float*)d_in[14];
    const float* Wpi = (const float*)d_in[15];
    const float* bpi = (const float*)d_in[16];
    const float* Wn  = (const float*)d_in[17];
    const float* bn  = (const float*)d_in[18];
    const float* Wp  = (const float*)d_in[19];
    const float* bp  = (const float*)d_in[20];

    // ---- workspace layout ----
    char* ws = (char*)d_ws;
    float* dinv = (float*)(ws + (0ull  << 20));
    int*   cnt  = (int*)  (ws + (1ull  << 20));
    int*   cur  = (int*)  (ws + (2ull  << 20));
    int*   rs   = (int*)  (ws + (3ull  << 20));
    int*   bsum = (int*)  (ws + (4ull  << 20));
    int*   boff = (int*)  (ws + (4ull  << 20) + (64 << 10));
    unsigned short* wpG1 = (unsigned short*)(ws + (5ull << 20));               // 16 KB
    unsigned short* wpG2 = (unsigned short*)(ws + (5ull << 20) + (128 << 10)); // 8 KB
    unsigned short* wpG3 = (unsigned short*)(ws + (5ull << 20) + (256 << 10)); // 8 KB
    unsigned short* wpC1 = (unsigned short*)(ws + (5ull << 20) + (384 << 10)); // 96 KB
    unsigned short* wpC2 = (unsigned short*)(ws + (5ull << 20) + (512 << 10)); // 24 KB
    unsigned short* wpC3 = (unsigned short*)(ws + (5ull << 20) + (640 << 10)); // 24 KB
    int* csr = (int*)(ws + (6ull << 20));                                      // 4 MB
    unsigned short* Xa = (unsigned short*)(ws + (16ull  << 20));  // 64ch  16.8 MB
    unsigned short* Xb = (unsigned short*)(ws + (36ull  << 20));  // 128ch 33.6 MB
    unsigned short* Xc = (unsigned short*)(ws + (72ull  << 20));  // 128ch 33.6 MB
    unsigned short* Xd = (unsigned short*)(ws + (108ull << 20));  // 32ch   8.4 MB
    unsigned short* Xe = (unsigned short*)(ws + (120ull << 20));  // 32ch   8.4 MB

    // ---- prep ----
    hipMemsetAsync(cnt, 0, TOT * sizeof(int), stream);
    hipMemsetAsync(cur, 0, TOT * sizeof(int), stream);
    k_pack<<<32,  256, 0, stream>>>(W1,  wpG1, 64, 64, 128, 1);
    k_pack<<<16,  256, 0, stream>>>(W2,  wpG2, 128, 128, 32, 1);
    k_pack<<<16,  256, 0, stream>>>(W3,  wpG3, 32, 32, 128, 1);
    k_pack<<<192, 256, 0, stream>>>(tW1, wpC1, 384, 128, 128, 3);
    k_pack<<<48,  256, 0, stream>>>(tW2, wpC2, 384, 128, 32, 3);
    k_pack<<<48,  256, 0, stream>>>(tW3, wpC3, 96, 32, 128, 3);

    // ---- CSR build + dinv ----
    k_count<<<NE / 256, 256, 0, stream>>>(dst, cnt, NE);
    k_dinv<<<TOT / 256, 256, 0, stream>>>(cnt, dinv);
    k_bsum<<<256, 256, 0, stream>>>(cnt, bsum);
    k_bscan<<<1, 256, 0, stream>>>(bsum, boff);
    k_scan<<<256, 256, 0, stream>>>(cnt, boff, rs);
    k_fill<<<NE / 256, 256, 0, stream>>>(src, dst, rs, cur, csr, NE);

    // ---- GCN layer 1: xs = x*dinv; agg1s = dinv*(xs_d + sum xs_src); h1 = relu(agg1s@W1+b1) ----
    k_scale64b<<<TOT * 8 / 256, 256, 0, stream>>>((const float4*)x, dinv, (uint4*)Xa);
    k_gatherb<3, 2><<<TOT * 8 / 256, 256, 0, stream>>>((const uint4*)Xa, rs, csr, dinv,
                                                       nullptr, (uint4*)Xb);
    k_mm<64, 128, 1, true, true, false>
        <<<TOT / 64, 256, 0, stream>>>(Xb, (const bf16x8*)wpG1, b1, dinv, Xc);

    // ---- GCN layer 2: zs2 = (h1@W2)*dinv; zs3 = relu(dinv*gather + b2)*dinv ----
    k_mm<128, 32, 1, false, false, true>
        <<<TOT / 64, 256, 0, stream>>>(Xc, (const bf16x8*)wpG2, nullptr, dinv, Xd);
    k_gatherb<2, 1><<<TOT * 4 / 256, 256, 0, stream>>>((const uint4*)Xd, rs, csr, dinv,
                                                       b2, (uint4*)Xe);

    // ---- GCN layer 3: agg3s = dinv*gather(zs3); h3 = relu(agg3s@W3+b3) ----
    k_gatherb<2, 2><<<TOT * 4 / 256, 256, 0, stream>>>((const uint4*)Xe, rs, csr, dinv,
                                                       nullptr, (uint4*)Xd);
    k_mm<32, 128, 1, true, true, false>
        <<<TOT / 64, 256, 0, stream>>>(Xd, (const bf16x8*)wpG3, b3, dinv, Xb);

    // ---- temporal convs ----
    k_mm<128, 128, 3, true, true, false>
        <<<TOT / 64, 256, 0, stream>>>(Xb, (const bf16x8*)wpC1, tb1, nullptr, Xc);
    k_mm<128, 32, 3, true, true, false>
        <<<TOT / 64, 256, 0, stream>>>(Xc, (const bf16x8*)wpC2, tb2, nullptr, Xd);
    k_mm<32, 128, 3, true, true, false>
        <<<TOT / 64, 256, 0, stream>>>(Xd, (const bf16x8*)wpC3, tb3, nullptr, Xb);

    // ---- heads ----
    k_heads<<<TOT / 256, 256, 0, stream>>>(Xb, Wpi, bpi, Wn, bn, Wp, bp, (float*)d_out);
}

// Round 4
// 368.598 us; speedup vs baseline: 6.4931x; 1.1186x over previous
//
#include <hip/hip_runtime.h>
#include <cmath>

// Problem constants (fixed by the reference)
constexpr int TOT = 131072;   // 32 graphs * 4096 nodes
constexpr int NE  = 1048576;  // edges
constexpr int NMASK = 4095;   // N-1, N=4096

typedef __attribute__((ext_vector_type(8))) short bf16x8;
typedef __attribute__((ext_vector_type(4))) float f32x4;

// ---- bf16 helpers (RNE) ----
__device__ inline float bf2f(unsigned int u16) {
    union { unsigned int i; float f; } x; x.i = u16 << 16; return x.f;
}
__device__ inline unsigned short f2bf(float f) {
    union { float f; unsigned int i; } x; x.f = f;
    unsigned int r = (x.i + 0x7fffu + ((x.i >> 16) & 1u)) >> 16;
    return (unsigned short)r;
}
__device__ inline void unpack8(uint4 v, float* f) {
    f[0] = bf2f(v.x & 0xffffu); f[1] = bf2f(v.x >> 16);
    f[2] = bf2f(v.y & 0xffffu); f[3] = bf2f(v.y >> 16);
    f[4] = bf2f(v.z & 0xffffu); f[5] = bf2f(v.z >> 16);
    f[6] = bf2f(v.w & 0xffffu); f[7] = bf2f(v.w >> 16);
}
__device__ inline uint4 pack8(const float* f) {
    uint4 v;
    v.x = (unsigned)f2bf(f[0]) | ((unsigned)f2bf(f[1]) << 16);
    v.y = (unsigned)f2bf(f[2]) | ((unsigned)f2bf(f[3]) << 16);
    v.z = (unsigned)f2bf(f[4]) | ((unsigned)f2bf(f[5]) << 16);
    v.w = (unsigned)f2bf(f[6]) | ((unsigned)f2bf(f[7]) << 16);
    return v;
}

// ================= adjacency build: per-dst linked list =================
// head[d] = last edge id with dst==d; nodes[e] = {src[e], prev edge id or -1}.
// Scattered traffic is only the 4B atomicExch on head (512 KB); the 8 MB
// nodes payload is written fully coalesced (vs the 76 MB HBM-side write
// amplification the scattered CSR fill showed in round 3).
__global__ __launch_bounds__(256) void k_link(const int* __restrict__ src,
                                              const int* __restrict__ dst,
                                              int* __restrict__ head,
                                              int2* __restrict__ nodes, int E) {
    int e = blockIdx.x * 256 + threadIdx.x;
    if (e >= E) return;
    int d = dst[e];
    int old = atomicExch(&head[d], e);
    nodes[e] = make_int2(src[e], old);
}

// walk chains once to get degree -> dinv
__global__ __launch_bounds__(256) void k_degchase(const int* __restrict__ head,
                                                  const int2* __restrict__ nodes,
                                                  float* __restrict__ dinv) {
    int d = blockIdx.x * 256 + threadIdx.x;   // d < TOT
    int c = 0;
    int e = head[d];
    while (e >= 0) { ++c; e = nodes[e].y; }
    dinv[d] = rsqrtf((float)c + 1.0f);        // +1 self-loop
}

// ================= weight packing into MFMA B-fragment order =================
// reader: lane reads wp[((kc*NT + nt)*64 + lane)*8 + j] = W[kc*32+(lane>>4)*8+j][nt*16+(lane&15)]
// taps==1: W row-major [K][COUT]; taps==3: original conv w[COUT][CIN][3], k = t*CIN + c.
// All six weight tensors packed in ONE launch (352 blocks) to cut dispatch count.
__global__ __launch_bounds__(256) void k_packall(
    const float* __restrict__ W1, const float* __restrict__ W2, const float* __restrict__ W3,
    const float* __restrict__ tW1, const float* __restrict__ tW2, const float* __restrict__ tW3,
    unsigned short* __restrict__ g1, unsigned short* __restrict__ g2, unsigned short* __restrict__ g3,
    unsigned short* __restrict__ c1, unsigned short* __restrict__ c2, unsigned short* __restrict__ c3) {
    int gid = blockIdx.x * 256 + threadIdx.x;
    const float* w; unsigned short* wp; int CIN, COUT, taps, idx;
    if      (gid <  8192) { w = W1;  wp = g1; CIN = 64;  COUT = 128; taps = 1; idx = gid; }
    else if (gid < 12288) { w = W2;  wp = g2; CIN = 128; COUT = 32;  taps = 1; idx = gid - 8192; }
    else if (gid < 16384) { w = W3;  wp = g3; CIN = 32;  COUT = 128; taps = 1; idx = gid - 12288; }
    else if (gid < 65536) { w = tW1; wp = c1; CIN = 128; COUT = 128; taps = 3; idx = gid - 16384; }
    else if (gid < 77824) { w = tW2; wp = c2; CIN = 128; COUT = 32;  taps = 3; idx = gid - 65536; }
    else if (gid < 90112) { w = tW3; wp = c3; CIN = 32;  COUT = 128; taps = 3; idx = gid - 77824; }
    else return;
    int j = idx & 7;
    int L = (idx >> 3) & 63;
    int f = idx >> 9;
    int NT = COUT >> 4;
    int kc = f / NT, nt = f - kc * NT;
    int k = kc * 32 + (L >> 4) * 8 + j;
    int n = nt * 16 + (L & 15);
    float v;
    if (taps == 1) v = w[k * COUT + n];
    else { int t = k / CIN, c = k - t * CIN; v = w[(n * CIN + c) * 3 + t]; }
    wp[idx] = f2bf(v);
}

// ================= node-wise =================

// xs = x * dinv -> bf16 (64 ch); one thread = 8 channels
__global__ __launch_bounds__(256) void k_scale64b(const float4* __restrict__ x,
                                                  const float* __restrict__ dinv,
                                                  uint4* __restrict__ out) {
    int t = blockIdx.x * 256 + threadIdx.x;   // t < TOT*8
    int row = t >> 3;
    float d = dinv[row];
    float4 v0 = x[t * 2], v1 = x[t * 2 + 1];
    float f[8] = { v0.x * d, v0.y * d, v0.z * d, v0.w * d,
                   v1.x * d, v1.y * d, v1.z * d, v1.w * d };
    out[t] = pack8(f);
}

// linked-list gather over bf16 rows, fp32 accumulate. LC = log2(C/8) threads/row.
// EPI==2: out = acc * dinv[d]                (pre-scale for the following GEMM)
// EPI==1: out = relu(acc*dinv + bias)*dinv   (layer-2 epilogue)
template<int LC, int EPI>
__global__ __launch_bounds__(256) void k_gatherb(const uint4* __restrict__ xs,
                                                 const int* __restrict__ head,
                                                 const int2* __restrict__ nodes,
                                                 const float* __restrict__ dinv,
                                                 const float* __restrict__ bias,
                                                 uint4* __restrict__ out) {
    int t = blockIdx.x * 256 + threadIdx.x;   // t < TOT << LC
    int d = t >> LC;
    int g = t & ((1 << LC) - 1);
    float a[8];
    unpack8(xs[t], a);                        // self-loop term
    int e = head[d];
    while (e >= 0) {
        int2 nd = nodes[e];                   // {src, next} in one 8B load
        float f[8];
        unpack8(xs[(nd.x << LC) + g], f);
#pragma unroll
        for (int j = 0; j < 8; ++j) a[j] += f[j];
        e = nd.y;
    }
    float dv = dinv[d];
    if (EPI == 1) {
#pragma unroll
        for (int j = 0; j < 8; ++j)
            a[j] = fmaxf(fmaf(a[j], dv, bias[g * 8 + j]), 0.0f) * dv;
    } else {
#pragma unroll
        for (int j = 0; j < 8; ++j) a[j] *= dv;
    }
    out[t] = pack8(a);
}

// ================= MFMA dense / conv1d =================
// Y[row][n] = act( sum_{t,c} X[row+t-1][c] * W[t*CIN+c][n] + bias[n] ) (TAPS=3)
// or plain GEMM (TAPS=1). X,Y bf16; W packed by k_packall; fp32 accumulate.
template<int CIN, int COUT, int TAPS, bool RELU, bool BIAS, bool SOUT>
__global__ __launch_bounds__(256) void k_mm(const unsigned short* __restrict__ x,
                                            const bf16x8* __restrict__ wp,
                                            const float* __restrict__ bias,
                                            const float* __restrict__ dinv,
                                            unsigned short* __restrict__ y) {
    constexpr int ROWS = 64;
    constexpr int HALO = (TAPS == 3) ? 1 : 0;
    constexpr int TR = ROWS + 2 * HALO;
    constexpr int SC = CIN + 8;               // stride 17/9/5 bank-quads: conflict-free b128
    constexpr int NCH = CIN / 32;             // K-chunks per tap
    constexpr int NK = TAPS * NCH;            // K-steps
    constexpr int NT = COUT / 16;             // col tiles total
    constexpr int WN = (COUT == 128) ? 2 : 1; // col tiles per wave
    constexpr int WM = (COUT == 128) ? 4 : 2; // row tiles per wave
    __shared__ __attribute__((aligned(16))) unsigned short tile[TR * SC];

    const int R0 = blockIdx.x * ROWS;
    const int n0 = R0 & NMASK; (void)n0;

    // stage X tile (bf16) into LDS, zero-padded halo at batch boundaries
    constexpr int NLD = TR * (CIN / 8);
    for (int idx = threadIdx.x; idx < NLD; idx += 256) {
        int tr = idx / (CIN / 8);
        int c8 = idx - tr * (CIN / 8);
        int ro = tr - HALO;
        bool valid = true;
        if (TAPS == 3) {
            if (ro < 0) valid = (n0 > 0);
            else if (ro >= ROWS) valid = (n0 + ROWS < 4096);
        }
        uint4 v = make_uint4(0, 0, 0, 0);
        if (valid) v = *(const uint4*)(x + (long)(R0 + ro) * CIN + c8 * 8);
        *(uint4*)(tile + tr * SC + c8 * 8) = v;
    }
    __syncthreads();

    const int lane = threadIdx.x & 63;
    const int w = threadIdx.x >> 6;
    const int l16 = lane & 15;
    const int q = lane >> 4;
    const int colbase = (COUT == 128) ? w * 32 : (w & 1) * 16;
    const int rowbase = (COUT == 128) ? 0 : (w >> 1) * 32;
    const int nt0 = colbase >> 4;

    f32x4 acc[WM][WN];
#pragma unroll
    for (int wm = 0; wm < WM; ++wm)
#pragma unroll
        for (int nt = 0; nt < WN; ++nt) acc[wm][nt] = (f32x4){0.f, 0.f, 0.f, 0.f};

    const bf16x8* __restrict__ wpl = wp + lane;

#pragma unroll
    for (int kc = 0; kc < NK; ++kc) {
        const int tap = (TAPS == 3) ? (kc / NCH) : 0;
        const int ch  = (TAPS == 3) ? (kc - tap * NCH) : kc;
        bf16x8 a[WM];
#pragma unroll
        for (int wm = 0; wm < WM; ++wm)
            a[wm] = *(const bf16x8*)(tile + (rowbase + wm * 16 + l16 + tap) * SC + ch * 32 + q * 8);
        bf16x8 b[WN];
#pragma unroll
        for (int nt = 0; nt < WN; ++nt)
            b[nt] = wpl[(kc * NT + nt0 + nt) * 64];
#pragma unroll
        for (int wm = 0; wm < WM; ++wm)
#pragma unroll
            for (int nt = 0; nt < WN; ++nt)
                acc[wm][nt] = __builtin_amdgcn_mfma_f32_16x16x32_bf16(a[wm], b[nt], acc[wm][nt], 0, 0, 0);
    }

    // epilogue: C/D layout col=lane&15, row=q*4+reg
#pragma unroll
    for (int wm = 0; wm < WM; ++wm) {
#pragma unroll
        for (int nt = 0; nt < WN; ++nt) {
            int col = colbase + nt * 16 + l16;
            float bi = BIAS ? bias[col] : 0.0f;
#pragma unroll
            for (int r = 0; r < 4; ++r) {
                int row = R0 + rowbase + wm * 16 + q * 4 + r;
                float v = acc[wm][nt][r] + bi;
                if (RELU) v = fmaxf(v, 0.0f);
                if (SOUT) v *= dinv[row];
                y[(long)row * COUT + col] = f2bf(v);
            }
        }
    }
}

// ================= heads (bf16 in, fp32 out) =================
__global__ __launch_bounds__(256) void k_heads(const unsigned short* __restrict__ xt,
                                               const float* __restrict__ Wpi, const float* __restrict__ bpi,
                                               const float* __restrict__ Wn,  const float* __restrict__ bn,
                                               const float* __restrict__ Wp,  const float* __restrict__ bp,
                                               float* __restrict__ out) {
    int row = blockIdx.x * 256 + threadIdx.x;
    if (row >= TOT) return;
    const uint4* xv = (const uint4*)(xt + (long)row * 128);
    float ap = 0.0f, an = 0.0f, aq = 0.0f;
#pragma unroll
    for (int c8 = 0; c8 < 16; ++c8) {
        float f[8];
        unpack8(xv[c8], f);
        int c = c8 * 8;
#pragma unroll
        for (int j = 0; j < 8; ++j) {
            ap = fmaf(f[j], Wpi[c + j], ap);
            an = fmaf(f[j], Wn[c + j], an);
            aq = fmaf(f[j], Wp[c + j], aq);
        }
    }
    float zpi = ap + bpi[0];
    float zn  = an + bn[0];
    float zp  = aq + bp[0];
    out[row] = 1.0f / (1.0f + expf(-zpi));
    out[TOT + row] = (zn > 20.0f) ? zn : log1pf(expf(zn));
    out[2 * TOT + row] = 1.0f / (1.0f + expf(-zp));
}

extern "C" void kernel_launch(void* const* d_in, const int* in_sizes, int n_in,
                              void* d_out, int out_size, void* d_ws, size_t ws_size,
                              hipStream_t stream) {
    const float* x   = (const float*)d_in[0];
    const int*   ei  = (const int*)d_in[1];
    const int*   src = ei;
    const int*   dst = ei + NE;
    const float* W1 = (const float*)d_in[3];
    const float* b1 = (const float*)d_in[4];
    const float* W2 = (const float*)d_in[5];
    const float* b2 = (const float*)d_in[6];
    const float* W3 = (const float*)d_in[7];
    const float* b3 = (const float*)d_in[8];
    const float* tW1 = (const float*)d_in[9];
    const float* tb1 = (const float*)d_in[10];
    const float* tW2 = (const float*)d_in[11];
    const float* tb2 = (const float*)d_in[12];
    const float* tW3 = (const float*)d_in[13];
    const float* tb3 = (const float*)d_in[14];
    const float* Wpi = (const float*)d_in[15];
    const float* bpi = (const float*)d_in[16];
    const float* Wn  = (const float*)d_in[17];
    const float* bn  = (const float*)d_in[18];
    const float* Wp  = (const float*)d_in[19];
    const float* bp  = (const float*)d_in[20];

    // ---- workspace layout ----
    char* ws = (char*)d_ws;
    float* dinv = (float*)(ws + (0ull << 20));            // 512 KB
    int*   head = (int*)  (ws + (1ull << 20));            // 512 KB
    int2*  nodes = (int2*)(ws + (2ull << 20));            // 8 MB
    unsigned short* wpG1 = (unsigned short*)(ws + (10ull << 20));               // 16 KB
    unsigned short* wpG2 = (unsigned short*)(ws + (10ull << 20) + (128 << 10)); // 8 KB
    unsigned short* wpG3 = (unsigned short*)(ws + (10ull << 20) + (256 << 10)); // 8 KB
    unsigned short* wpC1 = (unsigned short*)(ws + (10ull << 20) + (384 << 10)); // 96 KB
    unsigned short* wpC2 = (unsigned short*)(ws + (10ull << 20) + (512 << 10)); // 24 KB
    unsigned short* wpC3 = (unsigned short*)(ws + (10ull << 20) + (640 << 10)); // 24 KB
    unsigned short* Xa = (unsigned short*)(ws + (16ull  << 20));  // 64ch  16.8 MB
    unsigned short* Xb = (unsigned short*)(ws + (36ull  << 20));  // 128ch 33.6 MB
    unsigned short* Xc = (unsigned short*)(ws + (72ull  << 20));  // 128ch 33.6 MB
    unsigned short* Xd = (unsigned short*)(ws + (108ull << 20));  // 32ch   8.4 MB
    unsigned short* Xe = (unsigned short*)(ws + (120ull << 20));  // 32ch   8.4 MB

    // ---- prep: head = -1, pack all weights in one launch ----
    hipMemsetAsync(head, 0xFF, TOT * sizeof(int), stream);
    k_packall<<<352, 256, 0, stream>>>(W1, W2, W3, tW1, tW2, tW3,
                                       wpG1, wpG2, wpG3, wpC1, wpC2, wpC3);

    // ---- adjacency (linked list) + dinv ----
    k_link<<<NE / 256, 256, 0, stream>>>(src, dst, head, nodes, NE);
    k_degchase<<<TOT / 256, 256, 0, stream>>>(head, nodes, dinv);

    // ---- GCN layer 1: xs = x*dinv; agg1s = dinv*(xs_d + sum xs_src); h1 = relu(agg1s@W1+b1) ----
    k_scale64b<<<TOT * 8 / 256, 256, 0, stream>>>((const float4*)x, dinv, (uint4*)Xa);
    k_gatherb<3, 2><<<TOT * 8 / 256, 256, 0, stream>>>((const uint4*)Xa, head, nodes, dinv,
                                                       nullptr, (uint4*)Xb);
    k_mm<64, 128, 1, true, true, false>
        <<<TOT / 64, 256, 0, stream>>>(Xb, (const bf16x8*)wpG1, b1, dinv, Xc);

    // ---- GCN layer 2: zs2 = (h1@W2)*dinv; zs3 = relu(dinv*gather + b2)*dinv ----
    k_mm<128, 32, 1, false, false, true>
        <<<TOT / 64, 256, 0, stream>>>(Xc, (const bf16x8*)wpG2, nullptr, dinv, Xd);
    k_gatherb<2, 1><<<TOT * 4 / 256, 256, 0, stream>>>((const uint4*)Xd, head, nodes, dinv,
                                                       b2, (uint4*)Xe);

    // ---- GCN layer 3: agg3s = dinv*gather(zs3); h3 = relu(agg3s@W3+b3) ----
    k_gatherb<2, 2><<<TOT * 4 / 256, 256, 0, stream>>>((const uint4*)Xe, head, nodes, dinv,
                                                       nullptr, (uint4*)Xd);
    k_mm<32, 128, 1, true, true, false>
        <<<TOT / 64, 256, 0, stream>>>(Xd, (const bf16x8*)wpG3, b3, dinv, Xb);

    // ---- temporal convs ----
    k_mm<128, 128, 3, true, true, false>
        <<<TOT / 64, 256, 0, stream>>>(Xb, (const bf16x8*)wpC1, tb1, nullptr, Xc);
    k_mm<128, 32, 3, true, true, false>
        <<<TOT / 64, 256, 0, stream>>>(Xc, (const bf16x8*)wpC2, tb2, nullptr, Xd);
    k_mm<32, 128, 3, true, true, false>
        <<<TOT / 64, 256, 0, stream>>>(Xd, (const bf16x8*)wpC3, tb3, nullptr, Xb);

    // ---- heads ----
    k_heads<<<TOT / 256, 256, 0, stream>>>(Xb, Wpi, bpi, Wn, bn, Wp, bp, (float*)d_out);
}